// Round 3
// baseline (117.530 us; speedup 1.0000x reference)
//
#include <hip/hip_runtime.h>
#include <math.h>

#define BB 524288
#define CC 10
#define TT 25
#define BLK 256
#define NPAIR (BB / 2)           // each thread handles 2 consecutive b's
#define NBLK (NPAIR / BLK)       // 1024 blocks
#define SLABF (BB * CC)          // floats per t-slab of eps

__global__ void init_out_kernel(float* out) {
    // out = logT - (1/B) * sum_b log(S_b)
    *out = logf((float)TT);
}

__global__ __launch_bounds__(256) void mc_nll_kernel(
    const float* __restrict__ mu,
    const float* __restrict__ ls2,
    const int*   __restrict__ y,
    const float* __restrict__ eps,
    float* __restrict__ out)
{
    const int i = blockIdx.x * BLK + threadIdx.x;   // pair index: b0=2i, b1=2i+1
    const size_t base = (size_t)i * (2 * CC);       // float offset of this pair's row

    const int2 yy  = *reinterpret_cast<const int2*>(y + 2 * i);
    const int  yi0 = yy.x, yi1 = yy.y;

    // ---- per-pair params: 20 floats of mu / log_sigma2, 80 B 16-aligned -> float4 ----
    float muv[2 * CC], sig[2 * CC];
    {
        const float4* m4 = reinterpret_cast<const float4*>(mu + base);
        const float4* s4 = reinterpret_cast<const float4*>(ls2 + base);
#pragma unroll
        for (int j = 0; j < 5; ++j) {
            float4 m = m4[j];
            float4 s = s4[j];
            muv[4 * j + 0] = m.x; muv[4 * j + 1] = m.y;
            muv[4 * j + 2] = m.z; muv[4 * j + 3] = m.w;
            sig[4 * j + 0] = __expf(0.5f * s.x);
            sig[4 * j + 1] = __expf(0.5f * s.y);
            sig[4 * j + 2] = __expf(0.5f * s.z);
            sig[4 * j + 3] = __expf(0.5f * s.w);
        }
    }

    float S0 = 0.0f, S1 = 0.0f;
    const float* ebase = eps + base;

    // logit_y <= logsumexp_c always => exp(v) = e_y / s in (0,1]; sum directly over t,
    // no online max needed. e_y is one of the 10 softmax exponentials (select in-loop).
    auto compute = [&](const float4 (&e)[5]) {
        float l[2 * CC];
#pragma unroll
        for (int j = 0; j < 5; ++j) {
            l[4 * j + 0] = fmaf(sig[4 * j + 0], e[j].x, muv[4 * j + 0]);
            l[4 * j + 1] = fmaf(sig[4 * j + 1], e[j].y, muv[4 * j + 1]);
            l[4 * j + 2] = fmaf(sig[4 * j + 2], e[j].z, muv[4 * j + 2]);
            l[4 * j + 3] = fmaf(sig[4 * j + 3], e[j].w, muv[4 * j + 3]);
        }
        float m0 = l[0], m1 = l[CC];
#pragma unroll
        for (int c = 1; c < CC; ++c) {
            m0 = fmaxf(m0, l[c]);
            m1 = fmaxf(m1, l[CC + c]);
        }
        float s0 = 0.0f, s1 = 0.0f, e0 = 0.0f, e1 = 0.0f;
#pragma unroll
        for (int c = 0; c < CC; ++c) {
            float x0 = __expf(l[c] - m0);
            float x1 = __expf(l[CC + c] - m1);
            s0 += x0; s1 += x1;
            e0 = (c == yi0) ? x0 : e0;
            e1 = (c == yi1) ? x1 : e1;
        }
        S0 = fmaf(e0, __builtin_amdgcn_rcpf(s0), S0);
        S1 = fmaf(e1, __builtin_amdgcn_rcpf(s1), S1);
    };

#define LOADE(buf, t)                                                          \
    {                                                                          \
        const float4* p =                                                      \
            reinterpret_cast<const float4*>(ebase + (size_t)(t) * SLABF);      \
        _Pragma("unroll") for (int j = 0; j < 5; ++j) (buf)[j] = p[j];         \
    }

    // ---- unroll-by-2 software prefetch: next t's 5 dwordx4 in flight during compute ----
    float4 eA[5], eB[5];
    LOADE(eA, 0);
    for (int p = 0; p < 12; ++p) {
        const int t = 2 * p;
        LOADE(eB, t + 1);
        compute(eA);
        LOADE(eA, t + 2);      // p=11 loads t=24
        compute(eB);
    }
    compute(eA);               // t = 24

    const float picked2 = __logf(S0) + __logf(S1);   // log S_b0 + log S_b1

    // ---- block reduction: wave shuffle -> LDS -> one atomic per block ----
    float x = picked2;
#pragma unroll
    for (int off = 32; off > 0; off >>= 1)
        x += __shfl_down(x, off, 64);

    __shared__ float wsum[4];
    const int lane = threadIdx.x & 63;
    const int wid  = threadIdx.x >> 6;
    if (lane == 0) wsum[wid] = x;
    __syncthreads();
    if (threadIdx.x == 0) {
        float bs = wsum[0] + wsum[1] + wsum[2] + wsum[3];
        atomicAdd(out, -bs * (1.0f / (float)BB));
    }
}

extern "C" void kernel_launch(void* const* d_in, const int* in_sizes, int n_in,
                              void* d_out, int out_size, void* d_ws, size_t ws_size,
                              hipStream_t stream) {
    const float* mu  = (const float*)d_in[0];
    const float* ls2 = (const float*)d_in[1];
    const int*   y   = (const int*)d_in[2];
    const float* eps = (const float*)d_in[3];
    float* out = (float*)d_out;

    hipLaunchKernelGGL(init_out_kernel, dim3(1), dim3(1), 0, stream, out);
    hipLaunchKernelGGL(mc_nll_kernel, dim3(NBLK), dim3(BLK), 0, stream,
                       mu, ls2, y, eps, out);
}

// Round 4
// 109.927 us; speedup vs baseline: 1.0692x; 1.0692x over previous
//
#include <hip/hip_runtime.h>
#include <math.h>

#define BB 524288
#define CC 10
#define TT 25
#define BLK 256
#define NBLK (BB / BLK)          // 2048 blocks
#define WSLAB (64 * CC)          // 640 floats: one wave's 64 rows for one t
#define SLABF ((size_t)BB * CC)  // eps floats per t

// global_load_lds: LDS dest = wave-uniform base + lane*size; global src per-lane.
#define GLL(src, dst, n)                                                    \
    __builtin_amdgcn_global_load_lds(                                       \
        (const __attribute__((address_space(1))) void*)(src),               \
        (__attribute__((address_space(3))) void*)(dst), n, 0, 0)

__global__ void init_out_kernel(float* out) {
    // out = logT - (1/B) * sum_b log(S_b)
    *out = logf((float)TT);
}

__global__ __launch_bounds__(256) void mc_nll_kernel(
    const float* __restrict__ mu,
    const float* __restrict__ ls2,
    const int*   __restrict__ y,
    const float* __restrict__ eps,
    float* __restrict__ out)
{
    // per-wave double-buffered slabs: 2 bufs x 4 waves x 640 floats = 20 KB
    __shared__ float slab[2][4][WSLAB];
    __shared__ float wsum[4];

    const int tid  = threadIdx.x;
    const int wid  = tid >> 6;
    const int lane = tid & 63;
    const int b    = blockIdx.x * BLK + tid;

    const int yi = y[b];

    // ---- per-b params (same as R1: float2, stride-40; tiny fraction of traffic) ----
    float muv[CC], sig[CC];
    {
        const float2* m2 = reinterpret_cast<const float2*>(mu  + (size_t)b * CC);
        const float2* s2 = reinterpret_cast<const float2*>(ls2 + (size_t)b * CC);
#pragma unroll
        for (int i = 0; i < CC / 2; ++i) {
            float2 m = m2[i];
            float2 s = s2[i];
            muv[2 * i]     = m.x;
            muv[2 * i + 1] = m.y;
            sig[2 * i]     = __expf(0.5f * s.x);
            sig[2 * i + 1] = __expf(0.5f * s.y);
        }
    }

    // wave's slice of eps for t: 640 contiguous floats
    const float* wbase = eps + (size_t)blockIdx.x * BLK * CC + wid * WSLAB;

    // stage one t-slab with perfectly-coalesced direct-to-LDS loads:
    // 2 x dwordx4 (1024 B each) + 2 x dword (256 B each) = 2560 B, 1 request/line
    auto stage = [&](int t, int bf) {
        const float* s = wbase + (size_t)t * SLABF;
        float*       d = &slab[bf][wid][0];
        GLL(s + 4 * lane,        d,        16);
        GLL(s + 256 + 4 * lane,  d + 256,  16);
        GLL(s + 512 + lane,      d + 512,  4);
        GLL(s + 576 + lane,      d + 576,  4);
    };

    stage(0, 0);

    // logit_y <= logsumexp_c always => exp(v) = e_y/s in (0,1]; direct sum over t
    // (verified exact vs ref in R3), no online max needed.
    float S  = 0.0f;
    int   bf = 0;
    for (int t = 0; t < TT; ++t) {
        // prior iteration's ds_reads fully drained before overwriting that buffer
        asm volatile("s_waitcnt lgkmcnt(0)" ::: "memory");
        if (t < TT - 1) {
            stage(t + 1, bf ^ 1);                              // next slab in flight
            asm volatile("s_waitcnt vmcnt(4)" ::: "memory");   // slab t landed
        } else {
            asm volatile("s_waitcnt vmcnt(0)" ::: "memory");
        }

        const float* row = &slab[bf][wid][lane * CC];
        float l[CC];
#pragma unroll
        for (int i = 0; i < CC / 2; ++i) {
            float2 e = *reinterpret_cast<const float2*>(row + 2 * i);
            l[2 * i]     = fmaf(sig[2 * i],     e.x, muv[2 * i]);
            l[2 * i + 1] = fmaf(sig[2 * i + 1], e.y, muv[2 * i + 1]);
        }
        float m = l[0];
#pragma unroll
        for (int c = 1; c < CC; ++c) m = fmaxf(m, l[c]);
        float s = 0.0f, ey = 0.0f;
#pragma unroll
        for (int c = 0; c < CC; ++c) {
            float x = __expf(l[c] - m);
            s += x;
            ey = (c == yi) ? x : ey;
        }
        S = fmaf(ey, __builtin_amdgcn_rcpf(s), S);
        bf ^= 1;
    }

    // ---- block reduction: wave shuffle -> LDS -> one atomic per block ----
    float x = __logf(S);
#pragma unroll
    for (int off = 32; off > 0; off >>= 1)
        x += __shfl_down(x, off, 64);

    if (lane == 0) wsum[wid] = x;
    __syncthreads();
    if (tid == 0) {
        float bs = wsum[0] + wsum[1] + wsum[2] + wsum[3];
        atomicAdd(out, -bs * (1.0f / (float)BB));
    }
}

extern "C" void kernel_launch(void* const* d_in, const int* in_sizes, int n_in,
                              void* d_out, int out_size, void* d_ws, size_t ws_size,
                              hipStream_t stream) {
    const float* mu  = (const float*)d_in[0];
    const float* ls2 = (const float*)d_in[1];
    const int*   y   = (const int*)d_in[2];
    const float* eps = (const float*)d_in[3];
    float* out = (float*)d_out;

    hipLaunchKernelGGL(init_out_kernel, dim3(1), dim3(1), 0, stream, out);
    hipLaunchKernelGGL(mc_nll_kernel, dim3(NBLK), dim3(BLK), 0, stream,
                       mu, ls2, y, eps, out);
}